// Round 1
// baseline (149.450 us; speedup 1.0000x reference)
//
#include <hip/hip_runtime.h>
#include <math.h>

// Problem constants
#define BB 16      // batch
#define LL 32      // L
#define AA 2046    // attributor cols
#define MM 2048    // M = A + 2
#define NROWS 192  // 6L

// ---------------------------------------------------------------------------
// Kernel 1: QKV projection.
//   qkv[c][b][l][m] = sum_{n=0..63} relu(raw[b, 64c+n, m]) * W2[64c+n, l]
// where raw[b,r,m] = user[b,r] (m==0) | att[b,r,m-1]*W1[r,m-1] | item[b,r] (m==2047)
// grid (mtile=8, chunk=3, b=16), block 256 — thread owns one m column.
// W2 is indexed wave-uniformly -> scalar loads, FMA takes SGPR operand.
// ---------------------------------------------------------------------------
__global__ __launch_bounds__(256) void proj_kernel(
    const float* __restrict__ user, const float* __restrict__ item,
    const float* __restrict__ att, const float* __restrict__ W1,
    const float* __restrict__ W2, float* __restrict__ qkv) {
  const int m = blockIdx.x * 256 + threadIdx.x;
  const int c = blockIdx.y;
  const int b = blockIdx.z;

  float acc[LL];
#pragma unroll
  for (int l = 0; l < LL; ++l) acc[l] = 0.f;

  const int row0 = c * 64;
  for (int n = 0; n < 64; ++n) {
    const int gn = row0 + n;
    float v;
    if (m == 0) {
      v = user[b * NROWS + gn];
    } else if (m == MM - 1) {
      v = item[b * NROWS + gn];
    } else {
      v = att[(size_t)(b * NROWS + gn) * AA + (m - 1)] *
          W1[(size_t)gn * AA + (m - 1)];
    }
    v = fmaxf(v, 0.f);
    const float* __restrict__ w2row = W2 + (size_t)gn * LL;  // uniform -> SMEM
#pragma unroll
    for (int l = 0; l < LL; ++l) acc[l] += v * w2row[l];
  }

  float* dst = qkv + (size_t)c * (BB * LL * MM) + (size_t)b * LL * MM + m;
#pragma unroll
  for (int l = 0; l < LL; ++l) dst[(size_t)l * MM] = acc[l];
}

// ---------------------------------------------------------------------------
// Kernel 2: per-n causal weights for m in {0, M-1} + weighted reduction.
//   c_j(n) = sigmoid(s_n,mj * w[n,mj] - s_mj,n * w[mj,n]) * adj[n,mj]
//   out[b,l,j] += sum_n V[b,l,n] * c_j(n)
// grid (split=16, b=16), block 128 — thread owns one n in phase 1.
// ---------------------------------------------------------------------------
__global__ __launch_bounds__(128) void attn_kernel(
    const float* __restrict__ adj, const float* __restrict__ iw,
    const float* __restrict__ qkv, float* __restrict__ out) {
  const int split = blockIdx.x;
  const int b = blockIdx.y;
  const int tid = threadIdx.x;

  __shared__ float K0s[LL], K1s[LL], Q0s[LL], Q1s[LL];
  __shared__ float c0s[128], c1s[128];

  const float* __restrict__ Q = qkv;
  const float* __restrict__ K = qkv + (size_t)BB * LL * MM;
  const float* __restrict__ V = qkv + (size_t)2 * BB * LL * MM;

  // stage the two special columns of Q and K for this batch
  if (tid < 32)
    K0s[tid] = K[((size_t)b * LL + tid) * MM + 0];
  else if (tid < 64)
    K1s[tid - 32] = K[((size_t)b * LL + (tid - 32)) * MM + (MM - 1)];
  else if (tid < 96)
    Q0s[tid - 64] = Q[((size_t)b * LL + (tid - 64)) * MM + 0];
  else
    Q1s[tid - 96] = Q[((size_t)b * LL + (tid - 96)) * MM + (MM - 1)];
  __syncthreads();

  const int n = split * 128 + tid;

  float s0 = 0.f, s1 = 0.f, t0 = 0.f, t1 = 0.f;
#pragma unroll
  for (int l = 0; l < LL; ++l) {
    const float qv = Q[((size_t)b * LL + l) * MM + n];  // coalesced over tid
    const float kv = K[((size_t)b * LL + l) * MM + n];
    s0 += qv * K0s[l];
    s1 += qv * K1s[l];
    t0 += Q0s[l] * kv;
    t1 += Q1s[l] * kv;
  }

  const float a_n0 = adj[(size_t)n * MM + 0];
  const float a_n1 = adj[(size_t)n * MM + (MM - 1)];
  const float wn0 = a_n0 * iw[(size_t)n * MM + 0];
  const float wn1 = a_n1 * iw[(size_t)n * MM + (MM - 1)];
  const float w0n = adj[n] * iw[n];  // row 0, coalesced
  const float w1n = adj[(size_t)(MM - 1) * MM + n] * iw[(size_t)(MM - 1) * MM + n];

  const float d0 = s0 * wn0 - t0 * w0n;
  const float d1 = s1 * wn1 - t1 * w1n;

  // numerically-stable sigmoid == exp(min(d,0)) / (exp(min(d,0)) + exp(min(-d,0)))
  const float e0 = expf(-fabsf(d0));
  const float e1 = expf(-fabsf(d1));
  const float sig0 = (d0 > 0.f) ? 1.f / (1.f + e0) : e0 / (1.f + e0);
  const float sig1 = (d1 > 0.f) ? 1.f / (1.f + e1) : e1 / (1.f + e1);

  c0s[tid] = sig0 * a_n0;
  c1s[tid] = sig1 * a_n1;
  __syncthreads();

  // phase 2: 64 outputs (l, j), 2 threads per output split the 128-n range
  const int p = tid >> 1;      // 0..63
  const int half = tid & 1;    // 0/1
  const int l = p & 31;
  const int j = p >> 5;
  const float* __restrict__ cs = (j ? c1s : c0s) + half * 64;
  const float* __restrict__ vrow =
      V + ((size_t)b * LL + l) * MM + split * 128 + half * 64;
  float acc = 0.f;
#pragma unroll 8
  for (int i = 0; i < 64; ++i) acc += vrow[i] * cs[i];
  atomicAdd(&out[b * (LL * 2) + l * 2 + j], acc);
}

extern "C" void kernel_launch(void* const* d_in, const int* in_sizes, int n_in,
                              void* d_out, int out_size, void* d_ws,
                              size_t ws_size, hipStream_t stream) {
  const float* user = (const float*)d_in[0];
  const float* item = (const float*)d_in[1];
  const float* att = (const float*)d_in[2];
  const float* adj = (const float*)d_in[3];
  const float* iw = (const float*)d_in[4];
  const float* W1 = (const float*)d_in[5];
  const float* W2 = (const float*)d_in[6];
  float* out = (float*)d_out;
  float* qkv = (float*)d_ws;  // 3 * 16 * 32 * 2048 floats = 12.6 MB

  hipMemsetAsync(d_out, 0, sizeof(float) * (size_t)out_size, stream);

  dim3 g1(MM / 256, 3, BB);
  proj_kernel<<<g1, 256, 0, stream>>>(user, item, att, W1, W2, qkv);

  dim3 g2(MM / 128, BB);
  attn_kernel<<<g2, 128, 0, stream>>>(adj, iw, qkv, out);
}

// Round 2
// 134.792 us; speedup vs baseline: 1.1087x; 1.1087x over previous
//
#include <hip/hip_runtime.h>
#include <math.h>

// Problem constants
#define BB 16      // batch
#define LL 32      // L
#define AA 2046    // attributor cols
#define MM 2048    // M = A + 2
#define NROWS 192  // 6L

// Workspace layout (floats):
//   uv[4][16][64]    u0,u1,v0,v1  (4096)
//   st[4][16][2048]  s0,s1,t0,t1  (131072)
//   c [2][16][2048]  c0,c1        (65536)

// ---------------------------------------------------------------------------
// Kernel 0: per-batch prep.
//   K0[l] = sum_{r=64..127} relu(user[b,r]) W2[r,l]   (Key col 0)
//   K1[l] = sum_{r=64..127} relu(item[b,r]) W2[r,l]   (Key col M-1)
//   Q0[l] = sum_{r=0..63}   relu(user[b,r]) W2[r,l]   (Query col 0)
//   Q1[l] = sum_{r=0..63}   relu(item[b,r]) W2[r,l]
//   u0[b,r] = sum_l W2[r,l]·K0[l]      (r in [0,64)   -> weights for s0)
//   u1[b,r] = sum_l W2[r,l]·K1[l]      (               weights for s1)
//   v0[b,r] = sum_l W2[64+r,l]·Q0[l]   (r in [0,64)   -> weights for t0)
//   v1[b,r] = sum_l W2[64+r,l]·Q1[l]
// ---------------------------------------------------------------------------
__global__ __launch_bounds__(256) void prep_kernel(
    const float* __restrict__ user, const float* __restrict__ item,
    const float* __restrict__ W2, float* __restrict__ uv) {
  const int b = blockIdx.x, t = threadIdx.x;
  __shared__ float KQ[4][LL];
  if (t < 128) {
    const int q = t >> 5, l = t & 31;
    const float* __restrict__ src = (q == 0 || q == 2) ? user : item;
    const int rbase = (q < 2) ? 64 : 0;
    float acc = 0.f;
#pragma unroll
    for (int r = 0; r < 64; ++r)
      acc += fmaxf(src[b * NROWS + rbase + r], 0.f) * W2[(rbase + r) * LL + l];
    KQ[q][l] = acc;
  }
  __syncthreads();
  const int which = t >> 6, r = t & 63;
  const int wrow = (which < 2) ? r : 64 + r;
  float acc = 0.f;
#pragma unroll
  for (int l = 0; l < LL; ++l) acc += W2[wrow * LL + l] * KQ[which][l];
  uv[which * (BB * 64) + b * 64 + r] = acc;
}

// ---------------------------------------------------------------------------
// Kernel A1: s/t dot products, fused through the projection.
//   z=0: s0[b,n] = sum_{r<64}  relu(raw[b,r,n])·u0[b,r], s1 with u1
//   z=1: t0[b,n] = sum_{r=64..127} relu(raw[b,r,n])·v0[b,r-64], t1 with v1
// raw[b,r,0]=user, raw[b,r,M-1]=item, else att·W1.
// grid (8 ntiles, 16 b, 2 z) = 256 blocks; coalesced over n.
// ---------------------------------------------------------------------------
__global__ __launch_bounds__(256) void st_kernel(
    const float* __restrict__ user, const float* __restrict__ item,
    const float* __restrict__ att, const float* __restrict__ W1,
    const float* __restrict__ uv, float* __restrict__ st) {
  const int n = blockIdx.x * 256 + threadIdx.x;
  const int b = blockIdx.y, z = blockIdx.z;
  const float* __restrict__ w0 = uv + (2 * z) * (BB * 64) + b * 64;
  const float* __restrict__ w1 = uv + (2 * z + 1) * (BB * 64) + b * 64;
  const int rbase = z * 64;
  const bool isU = (n == 0), isI = (n == MM - 1);
  const int col = (isU || isI) ? 0 : (n - 1);  // clamped: keeps address valid
  float a0 = 0.f, a1 = 0.f;
#pragma unroll 16
  for (int r = 0; r < 64; ++r) {
    const int gr = b * NROWS + rbase + r;
    float v = isU ? user[gr]
                  : (isI ? item[gr]
                         : att[(size_t)gr * AA + col] *
                               W1[(size_t)(rbase + r) * AA + col]);
    v = fmaxf(v, 0.f);
    a0 += v * w0[r];
    a1 += v * w1[r];
  }
  st[(2 * z) * (BB * MM) + b * MM + n] = a0;
  st[(2 * z + 1) * (BB * MM) + b * MM + n] = a1;
}

// ---------------------------------------------------------------------------
// Kernel A2: causal weights for target cols {0, M-1}.
//   d0 = s0·adj[n,0]·iw[n,0] − t0·adj[0,n]·iw[0,n];  c0 = sigmoid(d0)·adj[n,0]
// (stable sigmoid == exp(min(d,0))/(exp(min(d,0))+exp(min(−d,0))))
// ---------------------------------------------------------------------------
__global__ __launch_bounds__(256) void cweight_kernel(
    const float* __restrict__ adj, const float* __restrict__ iw,
    const float* __restrict__ st, float* __restrict__ c) {
  const int idx = blockIdx.x * 256 + threadIdx.x;  // 16*2048
  const int b = idx >> 11, n = idx & (MM - 1);
  const float s0 = st[0 * (BB * MM) + b * MM + n];
  const float s1 = st[1 * (BB * MM) + b * MM + n];
  const float t0 = st[2 * (BB * MM) + b * MM + n];
  const float t1 = st[3 * (BB * MM) + b * MM + n];
  const float an0 = adj[(size_t)n * MM];
  const float an1 = adj[(size_t)n * MM + (MM - 1)];
  const float wn0 = an0 * iw[(size_t)n * MM];
  const float wn1 = an1 * iw[(size_t)n * MM + (MM - 1)];
  const float w0n = adj[n] * iw[n];
  const float w1n =
      adj[(size_t)(MM - 1) * MM + n] * iw[(size_t)(MM - 1) * MM + n];
  const float d0 = s0 * wn0 - t0 * w0n;
  const float d1 = s1 * wn1 - t1 * w1n;
  const float e0 = expf(-fabsf(d0));
  const float e1 = expf(-fabsf(d1));
  const float sig0 = (d0 > 0.f) ? 1.f / (1.f + e0) : e0 / (1.f + e0);
  const float sig1 = (d1 > 0.f) ? 1.f / (1.f + e1) : e1 / (1.f + e1);
  c[b * MM + n] = sig0 * an0;
  c[BB * MM + b * MM + n] = sig1 * an1;
}

// ---------------------------------------------------------------------------
// Kernel B: g_j[b,r] = sum_n relu(raw[b,128+rv,n])·c_j[b,n], then
//   out[b,l,j] += W2[128+rv,l]·g_j  (atomic).
// grid (64 rv, 16 b) = 1024 blocks, 256 threads, 8 coalesced n/thread.
// ---------------------------------------------------------------------------
__global__ __launch_bounds__(256) void gather_kernel(
    const float* __restrict__ user, const float* __restrict__ item,
    const float* __restrict__ att, const float* __restrict__ W1,
    const float* __restrict__ c, const float* __restrict__ W2,
    float* __restrict__ out) {
  const int rv = blockIdx.x, b = blockIdx.y, tid = threadIdx.x;
  const int r = 128 + rv;
  const int gr = b * NROWS + r;
  const float uval = fmaxf(user[gr], 0.f);
  const float ival = fmaxf(item[gr], 0.f);
  const float* __restrict__ c0 = c + b * MM;
  const float* __restrict__ c1 = c + BB * MM + b * MM;
  float g0 = 0.f, g1 = 0.f;
#pragma unroll
  for (int i = 0; i < 8; ++i) {
    const int n = i * 256 + tid;
    const bool isU = (n == 0), isI = (n == MM - 1);
    const int col = (isU || isI) ? 0 : (n - 1);
    float v = isU ? uval
                  : (isI ? ival
                         : fmaxf(att[(size_t)gr * AA + col] *
                                     W1[(size_t)r * AA + col],
                                 0.f));
    g0 += v * c0[n];
    g1 += v * c1[n];
  }
  __shared__ float r0[256], r1[256];
  r0[tid] = g0;
  r1[tid] = g1;
  __syncthreads();
  for (int s = 128; s > 0; s >>= 1) {
    if (tid < s) {
      r0[tid] += r0[tid + s];
      r1[tid] += r1[tid + s];
    }
    __syncthreads();
  }
  if (tid < 64) {
    const int l = tid & 31, j = tid >> 5;
    const float g = j ? r1[0] : r0[0];
    atomicAdd(&out[b * (LL * 2) + l * 2 + j], W2[r * LL + l] * g);
  }
}

extern "C" void kernel_launch(void* const* d_in, const int* in_sizes, int n_in,
                              void* d_out, int out_size, void* d_ws,
                              size_t ws_size, hipStream_t stream) {
  const float* user = (const float*)d_in[0];
  const float* item = (const float*)d_in[1];
  const float* att = (const float*)d_in[2];
  const float* adj = (const float*)d_in[3];
  const float* iw = (const float*)d_in[4];
  const float* W1 = (const float*)d_in[5];
  const float* W2 = (const float*)d_in[6];
  float* out = (float*)d_out;

  float* uv = (float*)d_ws;                 // 4096 floats
  float* st = uv + 4 * BB * 64;             // 131072 floats
  float* c = st + 4 * BB * MM;              // 65536 floats

  hipMemsetAsync(d_out, 0, sizeof(float) * (size_t)out_size, stream);

  prep_kernel<<<dim3(BB), 256, 0, stream>>>(user, item, W2, uv);
  st_kernel<<<dim3(MM / 256, BB, 2), 256, 0, stream>>>(user, item, att, W1, uv,
                                                       st);
  cweight_kernel<<<dim3(BB * MM / 256), 256, 0, stream>>>(adj, iw, st, c);
  gather_kernel<<<dim3(64, BB), 256, 0, stream>>>(user, item, att, W1, c, W2,
                                                  out);
}